// Round 1
// baseline (135.845 us; speedup 1.0000x reference)
//
#include <hip/hip_runtime.h>

// T=8192 frames, D=256, P=64 phones, K=128 centers/phone
#define T_FRAMES 8192
#define D_DIM    256
#define P_PHONES 64
#define K_CENT   128
#define TILE_F   16
#define BUCKET_CAP 256       // max per-phone count ~128+4sigma ≈ 173 << 256
#define SLOTS_PP   16        // 256/16 slots per phone
#define MARGIN   1.0f        // f16 coarse d2 error bound (worst ~0.4) -> 2.5x headroom

// ws byte layout
#define WS_NORMS  0                      // float[8192]          32 KB
#define WS_FIDX   32768                  // int[64*256]          64 KB
#define WS_DESC   98304                  // int4[1024]           16 KB
#define WS_CH     131072                 // _Float16[64*128*256]  4 MB

typedef _Float16 half8 __attribute__((ext_vector_type(8)));
typedef float    f32x4 __attribute__((ext_vector_type(4)));

// ---------------- K1: prep (light) ----------------
// b 0..127:   convert centers->f16 (cH) + fused fp32 row norms
// b 128..191: bucket block for phone j = b-128 (ballot compaction)
__global__ __launch_bounds__(1024) void qr_prep_kernel(const float* __restrict__ centers,
                                                       const int* __restrict__ phones,
                                                       float* __restrict__ norms,
                                                       int* __restrict__ fidx,
                                                       int4* __restrict__ desc,
                                                       _Float16* __restrict__ cH) {
    const int b    = blockIdx.x;
    const int tid  = threadIdx.x;
    const int w    = tid >> 6;
    const int lane = tid & 63;

    if (b < 128) {   // 64 center rows per block; wave w slice k covers row k*16+w
#pragma unroll
        for (int k = 0; k < 4; ++k) {
            const size_t e = (size_t)b * 16384 + (size_t)k * 4096 + (size_t)tid * 4;
            const float4 v = *(const float4*)(centers + e);
            union { _Float16 hf[4]; uint2 u; } pk;
            pk.hf[0] = (_Float16)v.x; pk.hf[1] = (_Float16)v.y;
            pk.hf[2] = (_Float16)v.z; pk.hf[3] = (_Float16)v.w;
            *(uint2*)(cH + e) = pk.u;
            float s = v.x * v.x + v.y * v.y + v.z * v.z + v.w * v.w;
#pragma unroll
            for (int off = 32; off; off >>= 1) s += __shfl_xor(s, off, 64);
            if (lane == 0) norms[b * 64 + k * 16 + w] = s;
        }
        return;
    }

    // bucket block: 16 waves, wave w scans frames [w*512, w*512+512)
    __shared__ int nsh;
    const int j = b - 128;
    if (tid == 0) nsh = 0;
    __syncthreads();
#pragma unroll
    for (int ch = 0; ch < 8; ++ch) {
        const int f = w * 512 + ch * 64 + lane;
        const bool mt = (phones[f] == j);
        const unsigned long long mask = __ballot(mt);
        const int cnt = __popcll(mask);
        if (cnt) {
            int base = 0;
            if (lane == 0) base = atomicAdd(&nsh, cnt);
            base = __shfl(base, 0, 64);
            if (mt) {
                const int pos = base + __popcll(mask & ((1ull << lane) - 1ull));
                if (pos < BUCKET_CAP) fidx[j * BUCKET_CAP + pos] = f;
            }
        }
    }
    __syncthreads();
    if (tid == 0) {
        const int c = nsh > BUCKET_CAP ? BUCKET_CAP : nsh;
#pragma unroll
        for (int k = 0; k < SLOTS_PP; ++k) {
            const int rem = c - k * TILE_F;
            const int fc  = rem < 0 ? 0 : (rem > TILE_F ? TILE_F : rem);
            desc[j * SLOTS_PP + k] = make_int4(j, j * BUCKET_CAP + k * TILE_F, fc, 0);
        }
    }
}

// ---------------- K2: main — one wave per 16-frame tile, ZERO barriers/LDS ----
// block = 4 waves = 4 slots of the SAME phone (L1/L2 B-pool reuse).
// A: fp32 h gathered + converted in-register with -2 folded in.
// C-init = ||c||^2  =>  acc IS the coarse d2 after the MFMA chain.
__global__ __launch_bounds__(256) void qr_main_kernel(const float* __restrict__ h,
                                                      const float* __restrict__ centers,
                                                      const float* __restrict__ norms,
                                                      const int* __restrict__ fidx,
                                                      const int4* __restrict__ desc,
                                                      const _Float16* __restrict__ cH,
                                                      float* __restrict__ out) {
    const int tid  = threadIdx.x;
    const int wave = tid >> 6;
    const int lane = tid & 63;
    const int m    = lane & 15;
    const int quad = lane >> 4;

    // phone = blockIdx&63 ; slot-k = (blockIdx>>6)*4 + wave  (dense slots dispatch first)
    const int slot = ((blockIdx.x & 63) << 4) + ((blockIdx.x >> 6) << 2) + wave;
    const int4 dsc = desc[slot];
    const int fcnt = dsc.z;
    if (fcnt == 0) return;                  // wave-level exit; no barriers anywhere
    const int p = dsc.x, fstart = dsc.y;

    const int fiA = fidx[fstart + min(m, fcnt - 1)];   // A row m = frame m (clamped pad)

    // A fragments: frame row m, dims quad*8 + s*32 + [0..8) ; -2 folded (exact pow2 scale)
    half8 aF[8];
    {
        const float* ap = h + (size_t)fiA * D_DIM + quad * 8;
#pragma unroll
        for (int s = 0; s < 8; ++s) {
            const float4 lo = *(const float4*)(ap + s * 32);
            const float4 hi = *(const float4*)(ap + s * 32 + 4);
            half8 t;
            t[0] = (_Float16)(-2.f * lo.x); t[1] = (_Float16)(-2.f * lo.y);
            t[2] = (_Float16)(-2.f * lo.z); t[3] = (_Float16)(-2.f * lo.w);
            t[4] = (_Float16)(-2.f * hi.x); t[5] = (_Float16)(-2.f * hi.y);
            t[6] = (_Float16)(-2.f * hi.z); t[7] = (_Float16)(-2.f * hi.w);
            aF[s] = t;
        }
    }

    // acc[ch] init = ||c_{ch*16+m}||^2 ; after MFMAs acc[ch][r] = d2(frame quad*4+r, center ch*16+m)
    f32x4 acc[8];
#pragma unroll
    for (int ch = 0; ch < 8; ++ch) {
        const float nrm = norms[(p << 7) + ch * 16 + m];
        f32x4 a = {nrm, nrm, nrm, nrm};
        acc[ch] = a;
    }
    const _Float16* bpbase = cH + (((size_t)(p << 7) + m) << 8) + quad * 8;
#pragma unroll
    for (int s = 0; s < 8; ++s) {           // s-outer: 8 independent acc chains stay interleaved
#pragma unroll
        for (int ch = 0; ch < 8; ++ch) {
            const half8 bF = *(const half8*)(bpbase + (size_t)ch * 4096 + s * 32);
            acc[ch] = __builtin_amdgcn_mfma_f32_16x16x32_f16(aF[s], bF, acc[ch], 0, 0, 0);
        }
    }

    // per-frame argmin: row (quad*4+r) reduced over ch in-register + 16-lane shfl group
    int  wreg[4];
    int  wcopy  = 0;
    bool anyNeg = false;
#pragma unroll
    for (int r = 0; r < 4; ++r) {
        float mn = fminf(fminf(fminf(acc[0][r], acc[1][r]), fminf(acc[2][r], acc[3][r])),
                         fminf(fminf(acc[4][r], acc[5][r]), fminf(acc[6][r], acc[7][r])));
#pragma unroll
        for (int off = 1; off <= 8; off <<= 1) mn = fminf(mn, __shfl_xor(mn, off, 64));
        const float tau = mn + MARGIN;
        int cnt = 0, cand = 0x7FFFFFFF;
#pragma unroll
        for (int ch = 0; ch < 8; ++ch) {
            if (acc[ch][r] < tau) { ++cnt; cand = min(cand, ch * 16 + m); }
        }
#pragma unroll
        for (int off = 1; off <= 8; off <<= 1) {
            cnt += __shfl_xor(cnt, off, 64);
            cand = min(cand, __shfl_xor(cand, off, 64));
        }
        const int wr = (cnt == 1) ? cand : -1;   // single candidate -> exact winner
        wreg[r] = wr;
        anyNeg |= (wr < 0);
        if (((lane >> 2) & 3) == r) wcopy = wr;  // copy lane l needs its quad's w[(l>>2)&3]
    }

    // exact fp32 rescue (rare, ~4% of frames): full 128-center scan, 2 centers/lane
    if (__any(anyNeg)) {
#pragma unroll
        for (int f = 0; f < TILE_F; ++f) {
            const int wf = __shfl(wreg[f & 3], (f >> 2) << 4, 64);  // readlane broadcast
            if (wf >= 0 || f >= fcnt) continue;                     // wave-uniform branch
            const int fiF = __shfl(fiA, f, 64);
            const float4* hp  = (const float4*)(h + (size_t)fiF * D_DIM);
            const float4* cp0 = (const float4*)(centers + ((size_t)(p << 7) + lane) * D_DIM);
            float s0 = 0.f, s1 = 0.f;
#pragma unroll 4
            for (int jx = 0; jx < 64; ++jx) {
                const float4 a  = hp[jx];
                const float4 b0 = cp0[jx];
                const float4 b1 = cp0[jx + 64 * 64];   // center lane+64
                s0 += a.x * b0.x + a.y * b0.y + a.z * b0.z + a.w * b0.w;
                s1 += a.x * b1.x + a.y * b1.y + a.z * b1.z + a.w * b1.w;
            }
            float best = norms[(p << 7) + lane] - 2.f * s0;
            int   bc   = lane;
            const float d1 = norms[(p << 7) + lane + 64] - 2.f * s1;
            if (d1 < best) { best = d1; bc = lane + 64; }   // lane+64 > lane: strict < keeps tie rule
#pragma unroll
            for (int off = 1; off < 64; off <<= 1) {        // lexicographic (d2, c) min -> jnp ties
                const float ob = __shfl_xor(best, off, 64);
                const int   oc = __shfl_xor(bc, off, 64);
                if (ob < best || (ob == best && oc < bc)) { best = ob; bc = oc; }
            }
            if ((lane >> 2) == f) wcopy = bc;
        }
    }

    // copy winning rows: 4 lanes/frame, 16 float4 each (64B segments)
    const int fr = lane >> 2, part = lane & 3;
    if (fr < fcnt) {
        const int fo = __shfl(fiA, fr, 64);
        const float4* src = (const float4*)(centers + ((size_t)(p << 7) + wcopy) * D_DIM) + part;
        float4*       dst = (float4*)(out + (size_t)fo * D_DIM) + part;
#pragma unroll
        for (int jx = 0; jx < 16; ++jx) dst[4 * jx] = src[4 * jx];
    }
}

extern "C" void kernel_launch(void* const* d_in, const int* in_sizes, int n_in,
                              void* d_out, int out_size, void* d_ws, size_t ws_size,
                              hipStream_t stream) {
    const float* h       = (const float*)d_in[0];
    const float* centers = (const float*)d_in[1];
    const int*   phones  = (const int*)d_in[2];
    float*       out     = (float*)d_out;

    char* ws = (char*)d_ws;
    float*    norms = (float*)(ws + WS_NORMS);
    int*      fidx  = (int*)(ws + WS_FIDX);
    int4*     desc  = (int4*)(ws + WS_DESC);
    _Float16* cH    = (_Float16*)(ws + WS_CH);

    qr_prep_kernel<<<192, 1024, 0, stream>>>(centers, phones, norms, fidx, desc, cH);
    qr_main_kernel<<<P_PHONES * 4, 256, 0, stream>>>(h, centers, norms, fidx, desc, cH, out);
}

// Round 2
// 130.123 us; speedup vs baseline: 1.0440x; 1.0440x over previous
//
#include <hip/hip_runtime.h>

// T=8192 frames, D=256, P=64 phones, K=128 centers/phone
#define T_FRAMES 8192
#define D_DIM    256
#define P_PHONES 64
#define K_CENT   128
#define TILE_F   16
#define BUCKET_CAP 256       // max per-phone count ~128+11sigma, safe
#define SLOTS_PP   16        // 256/16 slots per phone
#define MARGIN   1.0f        // f16 coarse d2 error bound (worst ~0.4) -> 2.5x headroom

// ws byte layout
#define WS_NORMS  0                      // float[8192]          32 KB
#define WS_FIDX   32768                  // int[64*256]          64 KB
#define WS_DESC   98304                  // int4[1024]           16 KB
#define WS_CH     131072                 // _Float16[64*128*256]  4 MB

typedef _Float16 half8 __attribute__((ext_vector_type(8)));
typedef float    f32x4 __attribute__((ext_vector_type(4)));

// ---------------- K1: prep (light) ----------------
// b 0..127:   convert centers->f16 (cH) + fused fp32 row norms
// b 128..191: bucket block for phone j = b-128 (ballot compaction)
__global__ __launch_bounds__(1024) void qr_prep_kernel(const float* __restrict__ centers,
                                                       const int* __restrict__ phones,
                                                       float* __restrict__ norms,
                                                       int* __restrict__ fidx,
                                                       int4* __restrict__ desc,
                                                       _Float16* __restrict__ cH) {
    const int b    = blockIdx.x;
    const int tid  = threadIdx.x;
    const int w    = tid >> 6;
    const int lane = tid & 63;

    if (b < 128) {   // 64 center rows per block; wave w slice k covers row k*16+w
#pragma unroll
        for (int k = 0; k < 4; ++k) {
            const size_t e = (size_t)b * 16384 + (size_t)k * 4096 + (size_t)tid * 4;
            const float4 v = *(const float4*)(centers + e);
            union { _Float16 hf[4]; uint2 u; } pk;
            pk.hf[0] = (_Float16)v.x; pk.hf[1] = (_Float16)v.y;
            pk.hf[2] = (_Float16)v.z; pk.hf[3] = (_Float16)v.w;
            *(uint2*)(cH + e) = pk.u;
            float s = v.x * v.x + v.y * v.y + v.z * v.z + v.w * v.w;
#pragma unroll
            for (int off = 32; off; off >>= 1) s += __shfl_xor(s, off, 64);
            if (lane == 0) norms[b * 64 + k * 16 + w] = s;
        }
        return;
    }

    // bucket block: 16 waves, wave w scans frames [w*512, w*512+512)
    __shared__ int nsh;
    const int j = b - 128;
    if (tid == 0) nsh = 0;
    __syncthreads();
#pragma unroll
    for (int ch = 0; ch < 8; ++ch) {
        const int f = w * 512 + ch * 64 + lane;
        const bool mt = (phones[f] == j);
        const unsigned long long mask = __ballot(mt);
        const int cnt = __popcll(mask);
        if (cnt) {
            int base = 0;
            if (lane == 0) base = atomicAdd(&nsh, cnt);
            base = __shfl(base, 0, 64);
            if (mt) {
                const int pos = base + __popcll(mask & ((1ull << lane) - 1ull));
                if (pos < BUCKET_CAP) fidx[j * BUCKET_CAP + pos] = f;
            }
        }
    }
    __syncthreads();
    if (tid == 0) {
        const int c = nsh > BUCKET_CAP ? BUCKET_CAP : nsh;
#pragma unroll
        for (int k = 0; k < SLOTS_PP; ++k) {
            const int rem = c - k * TILE_F;
            const int fc  = rem < 0 ? 0 : (rem > TILE_F ? TILE_F : rem);
            desc[j * SLOTS_PP + k] = make_int4(j, j * BUCKET_CAP + k * TILE_F, fc, 0);
        }
    }
}

// ---------------- K2: main ----------------
// block = one 16-frame tile x 128 centers; wave w owns centers [w*32, w*32+32).
// B slice lives entirely in registers (16 half8); -2 folded into A; ||c||^2 is
// the MFMA C-init so acc IS coarse d2. Cross-wave argmin via ~1KB LDS.
__global__ __launch_bounds__(256, 2) void qr_main_kernel(const float* __restrict__ h,
                                                         const float* __restrict__ centers,
                                                         const float* __restrict__ norms,
                                                         const int* __restrict__ fidx,
                                                         const int4* __restrict__ desc,
                                                         const _Float16* __restrict__ cH,
                                                         float* __restrict__ out) {
    __shared__ float sMin[4][TILE_F];
    __shared__ int   sCnt[4][TILE_F];
    __shared__ int   sCand[4][TILE_F];
    __shared__ int   sWin[TILE_F];
    __shared__ int   sRl[TILE_F];
    __shared__ int   sRn;

    const int4 dsc = desc[blockIdx.x];
    const int fcnt = dsc.z;
    if (fcnt == 0) return;                 // block-uniform exit
    const int p = dsc.x, fstart = dsc.y;

    const int tid  = threadIdx.x;
    const int wave = tid >> 6;
    const int lane = tid & 63;
    const int m    = lane & 15;
    const int quad = lane >> 4;

    if (tid == 0) sRn = 0;

    // frame index for A row m (clamped pad for partial tiles)
    const int fiA = fidx[fstart + min(m, fcnt - 1)];

    // B: this wave's 32-center slice, fully register-resident (32 VGPRs)
    const _Float16* bp = cH + (((size_t)(p << 7) + (wave << 5) + m) << 8) + quad * 8;
    half8 bF[2][8];
#pragma unroll
    for (int ch = 0; ch < 2; ++ch)
#pragma unroll
        for (int s = 0; s < 8; ++s)
            bF[ch][s] = *(const half8*)(bp + ((size_t)ch << 12) + s * 32);

    // A: gather h row, convert with -2 folded (exact pow2 scale)
    half8 aF[8];
    {
        const float* ap = h + (size_t)fiA * D_DIM + quad * 8;
#pragma unroll
        for (int s = 0; s < 8; ++s) {
            const float4 lo = *(const float4*)(ap + s * 32);
            const float4 hi = *(const float4*)(ap + s * 32 + 4);
            half8 t;
            t[0] = (_Float16)(-2.f * lo.x); t[1] = (_Float16)(-2.f * lo.y);
            t[2] = (_Float16)(-2.f * lo.z); t[3] = (_Float16)(-2.f * lo.w);
            t[4] = (_Float16)(-2.f * hi.x); t[5] = (_Float16)(-2.f * hi.y);
            t[6] = (_Float16)(-2.f * hi.z); t[7] = (_Float16)(-2.f * hi.w);
            aF[s] = t;
        }
    }

    // acc[ch] init = ||c||^2  ->  acc[ch][r] = coarse d2(frame quad*4+r, center w*32+ch*16+m)
    f32x4 acc[2];
#pragma unroll
    for (int ch = 0; ch < 2; ++ch) {
        const float nrm = norms[(p << 7) + (wave << 5) + ch * 16 + m];
        f32x4 a = {nrm, nrm, nrm, nrm};
        acc[ch] = a;
    }
#pragma unroll
    for (int s = 0; s < 8; ++s) {
        acc[0] = __builtin_amdgcn_mfma_f32_16x16x32_f16(aF[s], bF[0][s], acc[0], 0, 0, 0);
        acc[1] = __builtin_amdgcn_mfma_f32_16x16x32_f16(aF[s], bF[1][s], acc[1], 0, 0, 0);
    }

    // per-frame partial min over this wave's 32 centers (16-lane shfl groups)
#pragma unroll
    for (int r = 0; r < 4; ++r) {
        float mn = fminf(acc[0][r], acc[1][r]);
#pragma unroll
        for (int off = 1; off <= 8; off <<= 1) mn = fminf(mn, __shfl_xor(mn, off, 64));
        if (m == 0) sMin[wave][quad * 4 + r] = mn;
    }
    __syncthreads();

    // global tau per frame; count candidates in this wave's slice
#pragma unroll
    for (int r = 0; r < 4; ++r) {
        const int f = quad * 4 + r;
        const float gm = fminf(fminf(sMin[0][f], sMin[1][f]), fminf(sMin[2][f], sMin[3][f]));
        const float tau = gm + MARGIN;
        int cnt = 0, cand = 0x7FFFFFFF;
#pragma unroll
        for (int ch = 0; ch < 2; ++ch) {
            if (acc[ch][r] < tau) { ++cnt; cand = min(cand, (wave << 5) + ch * 16 + m); }
        }
#pragma unroll
        for (int off = 1; off <= 8; off <<= 1) {
            cnt += __shfl_xor(cnt, off, 64);
            cand = min(cand, __shfl_xor(cand, off, 64));
        }
        if (m == 0) { sCnt[wave][f] = cnt; sCand[wave][f] = cand; }
    }
    __syncthreads();

    // combine: unique candidate -> winner; else enqueue exact rescue
    if (tid < TILE_F) {
        const int tc = sCnt[0][tid] + sCnt[1][tid] + sCnt[2][tid] + sCnt[3][tid];
        const int cd = min(min(sCand[0][tid], sCand[1][tid]), min(sCand[2][tid], sCand[3][tid]));
        if (tc == 1) sWin[tid] = cd;
        else if (tid < fcnt) sRl[atomicAdd(&sRn, 1)] = tid;
    }
    __syncthreads();

    // exact fp32 rescue (rare): one wave per listed frame, rolled loop
    const int rn = sRn;
    for (int ridx = wave; ridx < rn; ridx += 4) {
        const int f2 = sRl[ridx];
        const int fi = fidx[fstart + f2];
        const float4* hp  = (const float4*)(h + (size_t)fi * D_DIM);
        const float4* cp0 = (const float4*)(centers + ((size_t)(p << 7) + lane) * D_DIM);
        float s0 = 0.f, s1 = 0.f;
#pragma unroll 4
        for (int jx = 0; jx < 64; ++jx) {
            const float4 a  = hp[jx];
            const float4 b0 = cp0[jx];
            const float4 b1 = cp0[jx + 4096];          // center row lane+64
            s0 += a.x * b0.x + a.y * b0.y + a.z * b0.z + a.w * b0.w;
            s1 += a.x * b1.x + a.y * b1.y + a.z * b1.z + a.w * b1.w;
        }
        float best = norms[(p << 7) + lane] - 2.f * s0;
        int   bc   = lane;
        const float d1 = norms[(p << 7) + lane + 64] - 2.f * s1;
        if (d1 < best) { best = d1; bc = lane + 64; }  // lane+64 > lane: strict < keeps tie rule
#pragma unroll
        for (int off = 1; off < 64; off <<= 1) {       // lexicographic (d2, c) min -> jnp ties
            const float ob = __shfl_xor(best, off, 64);
            const int   oc = __shfl_xor(bc, off, 64);
            if (ob < best || (ob == best && oc < bc)) { best = ob; bc = oc; }
        }
        if (lane == 0) sWin[f2] = bc;
    }
    __syncthreads();

    // copy winning rows: 16 threads/frame, 4 float4 each
    const int f = tid >> 4, part = tid & 15;
    if (f < fcnt) {
        const int fo = fidx[fstart + f];
        const float4* src = (const float4*)(centers + ((size_t)(p << 7) + sWin[f]) * D_DIM);
        float4*       dst = (float4*)(out + (size_t)fo * D_DIM);
#pragma unroll
        for (int jx = 0; jx < 4; ++jx) dst[part + 16 * jx] = src[part + 16 * jx];
    }
}

extern "C" void kernel_launch(void* const* d_in, const int* in_sizes, int n_in,
                              void* d_out, int out_size, void* d_ws, size_t ws_size,
                              hipStream_t stream) {
    const float* h       = (const float*)d_in[0];
    const float* centers = (const float*)d_in[1];
    const int*   phones  = (const int*)d_in[2];
    float*       out     = (float*)d_out;

    char* ws = (char*)d_ws;
    float*    norms = (float*)(ws + WS_NORMS);
    int*      fidx  = (int*)(ws + WS_FIDX);
    int4*     desc  = (int4*)(ws + WS_DESC);
    _Float16* cH    = (_Float16*)(ws + WS_CH);

    qr_prep_kernel<<<192, 1024, 0, stream>>>(centers, phones, norms, fidx, desc, cH);
    qr_main_kernel<<<P_PHONES * SLOTS_PP, 256, 0, stream>>>(h, centers, norms, fidx, desc, cH, out);
}